// Round 9
// baseline (2048.679 us; speedup 1.0000x reference)
//
#include <hip/hip_runtime.h>

#define SEQ 2048
#define BATCH 512
#define HDIM 128

typedef float f32x2 __attribute__((ext_vector_type(2)));

__device__ __forceinline__ float fast_tanh(float x) {
    // tanh(x) = 1 - 2/(exp(2x)+1); exact saturation at +/-inf.
    float e = __expf(2.0f * x);
    return fmaf(-2.0f, __builtin_amdgcn_rcpf(e + 1.0f), 1.0f);
}

// x + dpp_mov<CTRL>(x); old=0 so unselected/invalid lanes contribute 0.
template<int CTRL>
__device__ __forceinline__ float dpp_add(float x) {
    return x + __int_as_float(__builtin_amdgcn_update_dpp(
        0, __float_as_int(x), CTRL, 0xf, 0xf, false));
}

__global__ __launch_bounds__(64, 1)
void odenet_scan_kernel(const float* __restrict__ x,
                        const float* __restrict__ W1,
                        const float* __restrict__ b1,
                        const float* __restrict__ W2,
                        const float* __restrict__ b2,
                        const float* __restrict__ W3,
                        const float* __restrict__ b3,
                        float* __restrict__ out)
{
    const int l = threadIdx.x;      // 0..63 — ONE wave, ONE chain, NO barriers
    const int b = blockIdx.x;       // chain (batch element)
    const int cA = 2 * l;           // column A: full K in registers
    const int cB = 2 * l + 1;       // column B: K in [64,128) regs, [0,64) LDS

    __shared__ float  xbuf[SEQ];        // 8 KB: all x for this chain
    __shared__ float4 wlds4[16][64];    // 16 KB: colB weights k=4g..4g+3, lane-major
    __shared__ float  h1s[HDIM];        // 0.5 KB

    // ---- one-time staging (single wave; no block sync needed) ----
    // x: 32 elems/lane
    for (int i = 0; i < 32; ++i)
        xbuf[i * 64 + l] = x[(i * 64 + l) * BATCH + b];
    // colB lower-K weights -> LDS, lane-major so step reads are contiguous.
    #pragma unroll
    for (int g = 0; g < 16; ++g) {
        float4 wv;
        wv.x = W2[(4 * g + 0) * HDIM + cB];
        wv.y = W2[(4 * g + 1) * HDIM + cB];
        wv.z = W2[(4 * g + 2) * HDIM + cB];
        wv.w = W2[(4 * g + 3) * HDIM + cB];
        wlds4[g][l] = wv;
    }
    // colA full-K weights in regs (64 f32x2 = 128 floats).
    f32x2 wA[64];
    #pragma unroll
    for (int i = 0; i < 64; ++i)
        wA[i] = f32x2{W2[(2 * i) * HDIM + cA], W2[(2 * i + 1) * HDIM + cA]};
    // colB upper-K weights in regs (32 f32x2 = 64 floats).
    f32x2 wB[32];
    #pragma unroll
    for (int i = 0; i < 32; ++i)
        wB[i] = f32x2{W2[(64 + 2 * i) * HDIM + cB], W2[(64 + 2 * i + 1) * HDIM + cB]};

    // h1 params for the two h-columns (2l, 2l+1) this lane produces.
    const float2 w1x = *reinterpret_cast<const float2*>(&W1[2 * l]);
    const float2 w1s = *reinterpret_cast<const float2*>(&W1[HDIM + 2 * l]);
    const float2 b1v = *reinterpret_cast<const float2*>(&b1[2 * l]);
    const float2 b2v = *reinterpret_cast<const float2*>(&b2[2 * l]);
    const float w3v0 = W3[2 * cA + 1];     // only column 1 of W3 survives
    const float w3v1 = W3[2 * cB + 1];
    const float b31  = b3[1];

    __syncthreads();   // single wave: just orders LDS staging vs. loop

    float s = 0.0f;
    float s_hold = 0.0f;
    float xn = xbuf[0];
    const float4* h4 = reinterpret_cast<const float4*>(h1s);

    for (int n = 0; n < SEQ; ++n) {
        // ---- layer 1: two h columns -> LDS.
        float ha = fast_tanh(fmaf(w1x.x, xn, fmaf(w1s.x, s, b1v.x)));
        float hb = fast_tanh(fmaf(w1x.y, xn, fmaf(w1s.y, s, b1v.y)));
        *reinterpret_cast<float2*>(&h1s[2 * l]) = make_float2(ha, hb);
        __builtin_amdgcn_wave_barrier();   // order in-wave LDS write -> reads

        // next step's x from LDS (broadcast, off critical path)
        float xnext = xbuf[(n + 1) & (SEQ - 1)];

        // ---- layer 2: cols cA (regs) + cB (half regs, half LDS stream).
        f32x2 accA = {0.0f, 0.0f}, accB = {0.0f, 0.0f};
        #pragma unroll
        for (int g = 0; g < 32; ++g) {        // k = 4g .. 4g+3
            float4 hv = h4[g];                // broadcast read
            f32x2 hp0 = {hv.x, hv.y};
            f32x2 hp1 = {hv.z, hv.w};
            accA = __builtin_elementwise_fma(wA[2 * g],     hp0, accA);
            accA = __builtin_elementwise_fma(wA[2 * g + 1], hp1, accA);
            if (g < 16) {                     // colB lower K: streamed
                float4 wv = wlds4[g][l];
                f32x2 w0 = {wv.x, wv.y};
                f32x2 w1 = {wv.z, wv.w};
                accB = __builtin_elementwise_fma(w0, hp0, accB);
                accB = __builtin_elementwise_fma(w1, hp1, accB);
            } else {                          // colB upper K: registers
                accB = __builtin_elementwise_fma(wB[2 * (g - 16)],     hp0, accB);
                accB = __builtin_elementwise_fma(wB[2 * (g - 16) + 1], hp1, accB);
            }
        }
        __builtin_amdgcn_wave_barrier();   // keep reads before next iter's write

        // ---- horizontal, tanh, W3 col-1 dot (full K in lane: no combine).
        float pA = accA.x + accA.y;
        float pB = accB.x + accB.y;
        float z = fast_tanh(pA + b2v.x) * w3v0;
        z = fmaf(fast_tanh(pB + b2v.y), w3v1, z);

        // ---- wave64 sum: row_shr/bcast cascade; full sum lands in lane 63.
        z = dpp_add<0x111>(z);   // row_shr:1
        z = dpp_add<0x112>(z);   // row_shr:2
        z = dpp_add<0x114>(z);   // row_shr:4
        z = dpp_add<0x118>(z);   // row_shr:8
        z = dpp_add<0x142>(z);   // row_bcast:15
        z = dpp_add<0x143>(z);   // row_bcast:31
        float y = __int_as_float(__builtin_amdgcn_readlane(__float_as_int(z), 63));

        s = s + y + b31;

        // ---- out batching: one scatter store per 64 steps.
        if (l == (n & 63)) s_hold = s;
        if ((n & 63) == 63) out[(n - 63 + l) * BATCH + b] = s_hold;

        xn = xnext;
    }
}

extern "C" void kernel_launch(void* const* d_in, const int* in_sizes, int n_in,
                              void* d_out, int out_size, void* d_ws, size_t ws_size,
                              hipStream_t stream) {
    const float* x  = (const float*)d_in[0];
    const float* W1 = (const float*)d_in[1];
    const float* b1 = (const float*)d_in[2];
    const float* W2 = (const float*)d_in[3];
    const float* b2 = (const float*)d_in[4];
    const float* W3 = (const float*)d_in[5];
    const float* b3 = (const float*)d_in[6];
    float* out = (float*)d_out;

    dim3 grid(BATCH);    // one chain per block
    dim3 block(64);      // ONE wave — barrier-free steps
    odenet_scan_kernel<<<grid, block, 0, stream>>>(x, W1, b1, W2, b2, W3, b3, out);
}

// Round 10
// 1056.631 us; speedup vs baseline: 1.9389x; 1.9389x over previous
//
#include <hip/hip_runtime.h>

#define SEQ 2048
#define BATCH 512
#define HDIM 128

typedef float f32x2 __attribute__((ext_vector_type(2)));

__device__ __forceinline__ float fast_tanh(float x) {
    // tanh(x) = 1 - 2/(exp(2x)+1); exact saturation at +/-inf.
    float e = __expf(2.0f * x);
    return fmaf(-2.0f, __builtin_amdgcn_rcpf(e + 1.0f), 1.0f);
}

// x + dpp(x); bound_ctrl=true -> out-of-range lanes read 0 (fusable v_add_dpp).
template<int CTRL>
__device__ __forceinline__ float dpp_add(float x) {
    return x + __int_as_float(__builtin_amdgcn_update_dpp(
        0, __float_as_int(x), CTRL, 0xf, 0xf, true));
}

__global__ __launch_bounds__(512, 1)
void odenet_scan_kernel(const float* __restrict__ x,
                        const float* __restrict__ W1,
                        const float* __restrict__ b1,
                        const float* __restrict__ W2,
                        const float* __restrict__ b2,
                        const float* __restrict__ W3,
                        const float* __restrict__ b3,
                        float* __restrict__ out)
{
    const int t  = threadIdx.x;
    const int l  = t & 63;            // lane
    const int wv = t >> 6;            // wave 0..7
    const int ch = wv >> 2;           // chain within block: 0 (waves 0-3), 1 (4-7)
    const int w  = wv & 3;            // wave within chain: owns cols [32w, 32w+32)
    const int pr = l >> 2;            // pair index: cols 32w+2pr, 32w+2pr+1
    const int kq = l & 3;             // K-quarter: k in [32kq, 32kq+32)
    const int c0 = 32 * w + 2 * pr;   // first of this lane's 2 output columns
    const int b0 = 2 * blockIdx.x;    // chains b0 (ch=0), b0+1 (ch=1)

    __shared__ float2 xbuf[SEQ];           // 16 KB: {x_chainA, x_chainB} per step
    __shared__ float  h1buf[8][4 * 36];    // per-wave padded h1 (group g at 36g)
    __shared__ float  ybuf[2][8];          // [parity][wave] scalar y-partials

    // ---- one-time: preload x for both chains (adjacent in memory).
    {
        float2 v[4];
        #pragma unroll
        for (int i = 0; i < 4; ++i)
            v[i] = *reinterpret_cast<const float2*>(&x[(i * 512 + t) * BATCH + b0]);
        #pragma unroll
        for (int i = 0; i < 4; ++i)
            xbuf[i * 512 + t] = v[i];
    }

    // ---- one-time: pin W2 sub-block: 2 cols x 32 k, K-packed into f32x2.
    //      (weights shared by both chains; identical per wave-group)
    f32x2 wA[16], wB[16];
    #pragma unroll
    for (int i = 0; i < 16; ++i) {
        const int k0 = 32 * kq + 2 * i;
        wA[i] = f32x2{W2[k0 * HDIM + c0],     W2[(k0 + 1) * HDIM + c0]};
        wB[i] = f32x2{W2[k0 * HDIM + c0 + 1], W2[(k0 + 1) * HDIM + c0 + 1]};
    }

    // h1 params for the two h-columns (2l, 2l+1) this lane produces (per wave).
    const float2 w1x = *reinterpret_cast<const float2*>(&W1[2 * l]);
    const float2 w1s = *reinterpret_cast<const float2*>(&W1[HDIM + 2 * l]);
    const float2 b1v = *reinterpret_cast<const float2*>(&b1[2 * l]);
    // layer-2/3 params; w3 pre-scaled by 0.25 (each col duplicated x4 in quad).
    const float2 b2v = *reinterpret_cast<const float2*>(&b2[c0]);
    const float w3s0 = W3[(c0 + 0) * 2 + 1] * 0.25f;
    const float w3s1 = W3[(c0 + 1) * 2 + 1] * 0.25f;
    const float b31  = b3[1];

    // h write offset: position p=2l -> group p>>5 (=l>>4), slot p&31.
    const int hoff = 36 * (l >> 4) + ((2 * l) & 31);
    const float4* h4 = reinterpret_cast<const float4*>(&h1buf[wv][36 * kq]);

    __syncthreads();   // preload visible to all waves

    float s = 0.0f;
    float s_hold = 0.0f;
    // this wave's chain x at step 0; pre1 = W1x*x + b1 hoisted off critical path
    float2 x0p = xbuf[0];
    float xc = ch ? x0p.y : x0p.x;
    float2 pre1 = make_float2(fmaf(w1x.x, xc, b1v.x), fmaf(w1x.y, xc, b1v.y));

    for (int n = 0; n < SEQ; ++n) {
        const int par = n & 1;

        // ---- layer 1: two h columns -> wave-private LDS (critical path:
        //      only one fma + tanh after s arrives; pre1 precomputed).
        float ha = fast_tanh(fmaf(w1s.x, s, pre1.x));
        float hb = fast_tanh(fmaf(w1s.y, s, pre1.y));
        *reinterpret_cast<float2*>(&h1buf[wv][hoff]) = make_float2(ha, hb);
        __builtin_amdgcn_wave_barrier();   // order in-wave LDS write -> reads

        // next step's x + next pre1 (broadcast read, off critical path)
        float2 xnp = xbuf[(n + 1) & (SEQ - 1)];
        float xn1 = ch ? xnp.y : xnp.x;
        pre1 = make_float2(fmaf(w1x.x, xn1, b1v.x), fmaf(w1x.y, xn1, b1v.y));

        // ---- layer 2: 2 cols x 32 K per lane; 8 b128 reads, 32 v_pk_fma_f32.
        f32x2 accA = {0.0f, 0.0f}, accB = {0.0f, 0.0f};
        #pragma unroll
        for (int i = 0; i < 8; ++i) {
            float4 hv = h4[i];
            f32x2 hp0 = {hv.x, hv.y};
            f32x2 hp1 = {hv.z, hv.w};
            accA = __builtin_elementwise_fma(wA[2 * i],     hp0, accA);
            accB = __builtin_elementwise_fma(wB[2 * i],     hp0, accB);
            accA = __builtin_elementwise_fma(wA[2 * i + 1], hp1, accA);
            accB = __builtin_elementwise_fma(wB[2 * i + 1], hp1, accB);
        }
        __builtin_amdgcn_wave_barrier();   // keep reads before next iter's write

        // ---- horizontal + K-quarter combine within quad (2 DPP adds per col).
        float p0 = accA.x + accA.y;
        float p1 = accB.x + accB.y;
        p0 = dpp_add<0xB1>(p0); p1 = dpp_add<0xB1>(p1);  // quad_perm(1,0,3,2)
        p0 = dpp_add<0x4E>(p0); p1 = dpp_add<0x4E>(p1);  // quad_perm(2,3,0,1)

        // ---- layer 2 tanh + W3 col-1 dot (cols duplicated x4; w3 prescaled).
        float z = fast_tanh(p0 + b2v.x) * w3s0;
        z = fmaf(fast_tanh(p1 + b2v.y), w3s1, z);

        // ---- wave64 sum: row_shr/bcast cascade; full sum lands in lane 63.
        z = dpp_add<0x111>(z);   // row_shr:1
        z = dpp_add<0x112>(z);   // row_shr:2
        z = dpp_add<0x114>(z);   // row_shr:4
        z = dpp_add<0x118>(z);   // row_shr:8
        z = dpp_add<0x142>(z);   // row_bcast:15
        z = dpp_add<0x143>(z);   // row_bcast:31

        if (l == 63) ybuf[par][wv] = z;    // this wave's 32-col partial
        __syncthreads();   // ONE barrier serves BOTH chains' steps

        const float4 yv = *reinterpret_cast<const float4*>(&ybuf[par][4 * ch]);
        s = s + ((yv.x + yv.y) + (yv.z + yv.w)) + b31;

        // ---- out batching: wave0 stores chain A, wave4 stores chain B.
        if (w == 0) {
            if (l == (n & 63)) s_hold = s;
            if ((n & 63) == 63) out[(n - 63 + l) * BATCH + b0 + ch] = s_hold;
        }
    }
}

extern "C" void kernel_launch(void* const* d_in, const int* in_sizes, int n_in,
                              void* d_out, int out_size, void* d_ws, size_t ws_size,
                              hipStream_t stream) {
    const float* x  = (const float*)d_in[0];
    const float* W1 = (const float*)d_in[1];
    const float* b1 = (const float*)d_in[2];
    const float* W2 = (const float*)d_in[3];
    const float* b2 = (const float*)d_in[4];
    const float* W3 = (const float*)d_in[5];
    const float* b3 = (const float*)d_in[6];
    float* out = (float*)d_out;

    dim3 grid(BATCH / 2);   // two chains per block (separate wave-groups)
    dim3 block(512);        // 8 waves: 0-3 chain A, 4-7 chain B
    odenet_scan_kernel<<<grid, block, 0, stream>>>(x, W1, b1, W2, b2, W3, b3, out);
}